// Round 1
// baseline (272.278 us; speedup 1.0000x reference)
//
#include <hip/hip_runtime.h>

// MI355X / gfx950. bf16 MFMA BERT attention with relu^2 "softmax".
// mfma_f32_16x16x32_bf16 layouts (HW-verified):
//   A: lane l holds A[m=l&15][k=(l>>4)*8+j]
//   B: lane l holds B[k=(l>>4)*8+j][n=l&15]
//   C/D: lane l reg r holds D[row=(l>>4)*4+r][col=l&15]
// mfma_f32_16x16x16_bf16 (K=16):
//   A: lane l holds A[m=l&15][k=(l>>4)*4+j]  <-- matches 16x16x32 C-layout
//   B: lane l holds B[k=(l>>4)*4+j][n=l&15]
// R8 attention: 8 waves/block (512 thr), 32 q-rows/wave -> 16 waves/CU
// (was 2 blocks/CU * 4 waves = 8). Raw s_barrier + counted vmcnt(2)
// replaces __syncthreads() (whose vmcnt(0) drain was serializing the
// glds prefetch every tile). S^T = K Q^T; relu^2(S^T) packed in-register
// as the A-operand of the PV 16x16x16 MFMA; K/V double-buffered glds LDS.

typedef __bf16 bf16x8 __attribute__((ext_vector_type(8)));
typedef __bf16 bf16x4 __attribute__((ext_vector_type(4)));
typedef short  s16x4  __attribute__((ext_vector_type(4)));
typedef float  f32x4  __attribute__((ext_vector_type(4)));
typedef float  floatx4 __attribute__((ext_vector_type(4)));

#define MFMA16(a, b, c) __builtin_amdgcn_mfma_f32_16x16x32_bf16(a, b, c, 0, 0, 0)
// K=16 bf16 MFMA (gfx90a+ builtin, instruction present on gfx950 per ISA)
#define MFMA16K16(a, b, c) \
    __builtin_amdgcn_mfma_f32_16x16x16bf16_1k(a, b, c, 0, 0, 0)

#define WAITCNT_VM2() __builtin_amdgcn_s_waitcnt(0x0F72)   // vmcnt(2)
#define BARRIER() __builtin_amdgcn_s_barrier()

__device__ __forceinline__ void glds16(const __bf16* g, __bf16* l) {
    __builtin_amdgcn_global_load_lds(
        (const __attribute__((address_space(1))) void*)g,
        (__attribute__((address_space(3))) void*)l, 16, 0, 0);
}

// ---------------------------------------------------------------------------
// fp32 -> bf16 conversion: X (8M elems) then Wq/Wk/Wv (1M each).
// ---------------------------------------------------------------------------
__global__ __launch_bounds__(256) void convert_kernel(
    const float* __restrict__ X, const float* __restrict__ Wq,
    const float* __restrict__ Wk, const float* __restrict__ Wv,
    __bf16* __restrict__ Xb, __bf16* __restrict__ Wqb,
    __bf16* __restrict__ Wkb, __bf16* __restrict__ Wvb)
{
    int blk = blockIdx.x;
    const float* src; __bf16* dst; size_t base;
    if (blk < 4096)      { src = X;  dst = Xb;  base = (size_t)blk * 2048; }
    else if (blk < 4608) { src = Wq; dst = Wqb; base = (size_t)(blk - 4096) * 2048; }
    else if (blk < 5120) { src = Wk; dst = Wkb; base = (size_t)(blk - 4608) * 2048; }
    else                 { src = Wv; dst = Wvb; base = (size_t)(blk - 5120) * 2048; }
    size_t off = base + (size_t)threadIdx.x * 8;
    floatx4 a = *(const floatx4*)(src + off);
    floatx4 c = *(const floatx4*)(src + off + 4);
    bf16x8 o;
    o[0] = (__bf16)a[0]; o[1] = (__bf16)a[1]; o[2] = (__bf16)a[2]; o[3] = (__bf16)a[3];
    o[4] = (__bf16)c[0]; o[5] = (__bf16)c[1]; o[6] = (__bf16)c[2]; o[7] = (__bf16)c[3];
    *(bf16x8*)(dst + off) = o;
}

// ---------------------------------------------------------------------------
// Fused QKV GEMM: out = Xb @ Wb.T + bias. glds staging + XOR swizzle.
// blockIdx.x: 0-7 -> Q, 8-15 -> K, 16-23 -> V(transposed).
// ---------------------------------------------------------------------------
__global__ __launch_bounds__(256) void qkv_gemm_kernel(
    const __bf16* __restrict__ Xb,
    const __bf16* __restrict__ Wqb, const __bf16* __restrict__ Wkb,
    const __bf16* __restrict__ Wvb,
    const float* __restrict__ bq, const float* __restrict__ bk,
    const float* __restrict__ bv,
    __bf16* __restrict__ qws, __bf16* __restrict__ kws, __bf16* __restrict__ vws)
{
    __shared__ __bf16 As[128 * 64];
    __shared__ __bf16 Bs[128 * 64];

    const int tid  = threadIdx.x;
    const int lane = tid & 63;
    const int wave = tid >> 6;
    const int wm   = (wave >> 1) * 64;
    const int wn   = (wave & 1) * 64;
    const int quad = lane >> 4;
    const int l16  = lane & 15;
    const int m0   = blockIdx.y * 128;

    const int sel = blockIdx.x >> 3;
    const bool vmode = (sel == 2);
    const __bf16* Wb = (sel == 0) ? Wqb : (sel == 1) ? Wkb : Wvb;
    const float* bias = (sel == 0) ? bq : (sel == 1) ? bk : bv;
    __bf16* outp = (sel == 0) ? qws : (sel == 1) ? kws : vws;
    const int n0 = (blockIdx.x & 7) * 128;

    const __bf16* Pa = vmode ? As : Bs;
    const __bf16* Pb = vmode ? Bs : As;
    const int woffA = vmode ? wm : wn;
    const int woffB = vmode ? wn : wm;

    f32x4 acc[4][4] = {};

    for (int k0 = 0; k0 < 1024; k0 += 64) {
        __syncthreads();
        #pragma unroll
        for (int i = 0; i < 4; ++i) {
            int r = wave * 32 + i * 8 + (lane >> 3);
            int c = (lane & 7) ^ (r & 7);
            glds16(Xb + (size_t)(m0 + r) * 1024 + k0 + c * 8,
                   &As[(wave * 32 + i * 8) * 64]);
            glds16(Wb + (size_t)(n0 + r) * 1024 + k0 + c * 8,
                   &Bs[(wave * 32 + i * 8) * 64]);
        }
        __syncthreads();

        #pragma unroll
        for (int kk8 = 0; kk8 < 8; kk8 += 4) {
            bf16x8 af[4], bfr[4];
            #pragma unroll
            for (int a = 0; a < 4; ++a)
                af[a] = *(const bf16x8*)&Pa[(woffA + a * 16 + l16) * 64 +
                                            (((kk8 + quad) ^ (l16 & 7)) * 8)];
            #pragma unroll
            for (int bb = 0; bb < 4; ++bb)
                bfr[bb] = *(const bf16x8*)&Pb[(woffB + bb * 16 + l16) * 64 +
                                              (((kk8 + quad) ^ (l16 & 7)) * 8)];
            #pragma unroll
            for (int a = 0; a < 4; ++a)
                #pragma unroll
                for (int bb = 0; bb < 4; ++bb)
                    acc[a][bb] = MFMA16(af[a], bfr[bb], acc[a][bb]);
        }
    }

    if (!vmode) {
        #pragma unroll
        for (int a = 0; a < 4; ++a) {
            int n = n0 + woffA + a * 16 + quad * 4;
            floatx4 bv4 = *(const floatx4*)&bias[n];
            int h = n >> 6, d0 = n & 63;
            #pragma unroll
            for (int bb = 0; bb < 4; ++bb) {
                int m = m0 + woffB + bb * 16 + l16;
                int bt = m >> 11, s = m & 2047;
                bf16x4 o;
                #pragma unroll
                for (int r = 0; r < 4; ++r)
                    o[r] = (__bf16)(acc[a][bb][r] + bv4[r]);
                *(bf16x4*)&outp[((size_t)(bt * 16 + h) * 2048 + s) * 64 + d0] = o;
            }
        }
    } else {
        #pragma unroll
        for (int a = 0; a < 4; ++a) {
            int m = m0 + woffA + a * 16 + quad * 4;
            int bt = m >> 11, s0 = m & 2047;
            #pragma unroll
            for (int bb = 0; bb < 4; ++bb) {
                int n = n0 + woffB + bb * 16 + l16;
                float bvv = bias[n];
                int h = n >> 6, d = n & 63;
                bf16x4 o;
                #pragma unroll
                for (int r = 0; r < 4; ++r)
                    o[r] = (__bf16)(acc[a][bb][r] + bvv);
                *(bf16x4*)&outp[((size_t)(bt * 16 + h) * 64 + d) * 2048 + s0] = o;
            }
        }
    }
}

// ---------------------------------------------------------------------------
// Attention R8: grid (8, 64); 8 waves/block (512 thr), 32 q-rows per wave.
// Same q coverage per block (256 rows) and same per-block staging traffic
// as R7, but 16 waves/CU instead of 8. Per 64-key tile: each wave stages
// 8 rows of K and 8 rows of V (1 glds each) into double-buffered swizzled
// LDS; counted vmcnt(2) + raw s_barrier keep the next-tile prefetch in
// flight across the barrier (no vmcnt(0) drain). S^T = K Q^T (16x16x32);
// relu^2 packed in-register as PV 16x16x16 A-operand; ctx fp32.
// ---------------------------------------------------------------------------
__global__ __launch_bounds__(512, 4) void attn_kernel(
    const __bf16* __restrict__ Q, const __bf16* __restrict__ K,
    const __bf16* __restrict__ Vt, const float* __restrict__ mask,
    float* __restrict__ out)
{
    __shared__ __bf16 Ks[2][64 * 64];   // [key][d], XOR-swizzled chunks
    __shared__ __bf16 Vs[2][64 * 64];   // [d][key], XOR-swizzled chunks

    const int tid  = threadIdx.x;
    const int lane = tid & 63;
    const int wave = tid >> 6;          // 0..7
    const int quad = lane >> 4;
    const int l16  = lane & 15;
    const int bh   = blockIdx.y;
    const int b    = bh >> 4;
    const int h    = bh & 15;
    const int q0   = blockIdx.x * 256 + wave * 32;

    const __bf16* Qb = Q  + (size_t)bh * 2048 * 64;
    const __bf16* Kb = K  + (size_t)bh * 2048 * 64;
    const __bf16* Vb = Vt + (size_t)bh * 64 * 2048;
    const float*  mb = mask + b * 2048;

    // staging lane geometry: each wave fills 8 rows of K and 8 rows of V.
    const int rb = wave * 8;                       // LDS row base this wave
    const int sr = rb + (lane >> 3);               // row this lane reads
    const int sc = ((lane & 7) ^ (sr & 7)) * 8;    // swizzled elem offset

    // Q fragments (B operand for S^T): lane n=l16 -> q, k = 8 contiguous d.
    bf16x8 aq[2][2];
    #pragma unroll
    for (int qi = 0; qi < 2; ++qi)
        #pragma unroll
        for (int kcd = 0; kcd < 2; ++kcd)
            aq[qi][kcd] = *(const bf16x8*)(Qb +
                (size_t)(q0 + qi * 16 + l16) * 64 + kcd * 32 + quad * 8);

    f32x4 co[2][4] = {};   // ctx[q-tile][d-tile], rows=q, cols=d

    // ---- stage tile 0 into buffer 0 (2 glds/wave) ----
    glds16(Kb + (size_t)sr * 64 + sc, &Ks[0][rb * 64]);
    glds16(Vb + (size_t)sr * 2048 + sc, &Vs[0][rb * 64]);

    for (int t = 0; t < 32; ++t) {
        const int k0 = t * 64;
        const int kn = (k0 + 64) & 2047;          // wrap: last prefetch benign
        const int nb = (t + 1) & 1;
        // ---- stage next tile (2 glds/wave) ----
        glds16(Kb + (size_t)(kn + sr) * 64 + sc, &Ks[nb][rb * 64]);
        glds16(Vb + (size_t)sr * 2048 + kn + sc, &Vs[nb][rb * 64]);
        WAITCNT_VM2();          // this tile's 2 glds (older) complete
        BARRIER();              // all waves' staging of tile t visible

        const __bf16* Kt = &Ks[t & 1][0];
        const __bf16* Vtile = &Vs[t & 1][0];

        // ---- S^T + relu^2, packed per 16-key chunk into PV A-frags ----
        bf16x4 pf[4][2];                           // [ki][qi]
        #pragma unroll
        for (int ki = 0; ki < 4; ++ki) {
            f32x4 st[2] = {};
            #pragma unroll
            for (int kcd = 0; kcd < 2; ++kcd) {
                int key = ki * 16 + l16;
                bf16x8 ak = *(const bf16x8*)&Kt[key * 64 +
                    (((kcd * 4 + quad) ^ (key & 7)) * 8)];
                #pragma unroll
                for (int qi = 0; qi < 2; ++qi)
                    st[qi] = MFMA16(ak, aq[qi][kcd], st[qi]);
            }
            floatx4 mk = *(const floatx4*)&mb[k0 + ki * 16 + quad * 4];
            #pragma unroll
            for (int qi = 0; qi < 2; ++qi) {
                bf16x4 pv;
                #pragma unroll
                for (int r = 0; r < 4; ++r) {
                    float x = st[qi][r] * 0.125f + mk[r];
                    x = fmaxf(x, 0.0f);
                    pv[r] = (__bf16)(x * x);
                }
                pf[ki][qi] = pv;
            }
        }

        // ---- PV: ctx[q][d] += P V via 16x16x16 (A=pf in registers) ----
        #pragma unroll
        for (int ki = 0; ki < 4; ++ki) {
            bf16x4 vb4[4];
            #pragma unroll
            for (int dt = 0; dt < 4; ++dt) {
                int d = dt * 16 + l16;
                int g = ki * 2 + (quad >> 1);       // global 8-elem chunk
                vb4[dt] = *(const bf16x4*)&Vtile[d * 64 +
                    ((g ^ (d & 7)) * 8) + (quad & 1) * 4];
            }
            #pragma unroll
            for (int qi = 0; qi < 2; ++qi) {
                s16x4 pa = __builtin_bit_cast(s16x4, pf[ki][qi]);
                #pragma unroll
                for (int dt = 0; dt < 4; ++dt)
                    co[qi][dt] = MFMA16K16(pa,
                        __builtin_bit_cast(s16x4, vb4[dt]), co[qi][dt]);
            }
        }
        BARRIER();              // everyone done reading buf t before overwrite
    }

    // Epilogue: ctx row = q = qi*16+quad*4+r, col = d = dt*16+l16.
    #pragma unroll
    for (int qi = 0; qi < 2; ++qi)
        #pragma unroll
        for (int r = 0; r < 4; ++r) {
            int q = q0 + qi * 16 + quad * 4 + r;
            float* orow = &out[(((size_t)b * 2048 + q) * 16 + h) * 64];
            #pragma unroll
            for (int dt = 0; dt < 4; ++dt)
                orow[dt * 16 + l16] = co[qi][dt][r];
        }
}

// ---------------------------------------------------------------------------
extern "C" void kernel_launch(void* const* d_in, const int* in_sizes, int n_in,
                              void* d_out, int out_size, void* d_ws, size_t ws_size,
                              hipStream_t stream) {
    const float* hidden = (const float*)d_in[0];   // [4,2048,1024]
    const float* mask   = (const float*)d_in[1];   // [4,1,1,2048]
    const float* Wq     = (const float*)d_in[2];
    const float* bq     = (const float*)d_in[3];
    const float* Wk     = (const float*)d_in[4];
    const float* bk     = (const float*)d_in[5];
    const float* Wv     = (const float*)d_in[6];
    const float* bv     = (const float*)d_in[7];
    float* out = (float*)d_out;

    __bf16* qws = (__bf16*)d_ws;                       // [64][2048][64]
    __bf16* kws = qws + (size_t)64 * 2048 * 64;        // [64][2048][64]
    __bf16* vws = kws + (size_t)64 * 2048 * 64;        // [64][64][2048]
    __bf16* Xb  = vws + (size_t)64 * 2048 * 64;        // [8192][1024]
    __bf16* Wqb = Xb  + (size_t)8192 * 1024;
    __bf16* Wkb = Wqb + (size_t)1024 * 1024;
    __bf16* Wvb = Wkb + (size_t)1024 * 1024;

    convert_kernel<<<dim3(5632), dim3(256), 0, stream>>>(hidden, Wq, Wk, Wv,
                                                         Xb, Wqb, Wkb, Wvb);
    qkv_gemm_kernel<<<dim3(24, 64), dim3(256), 0, stream>>>(Xb, Wqb, Wkb, Wvb,
                                                            bq, bk, bv,
                                                            qws, kws, vws);
    attn_kernel<<<dim3(8, 64), dim3(512), 0, stream>>>(qws, kws, vws, mask, out);
}

// Round 2
// 268.859 us; speedup vs baseline: 1.0127x; 1.0127x over previous
//
#include <hip/hip_runtime.h>

// MI355X / gfx950. bf16 MFMA BERT attention with relu^2 "softmax".
// mfma_f32_16x16x32_bf16 layouts (HW-verified):
//   A: lane l holds A[m=l&15][k=(l>>4)*8+j]
//   B: lane l holds B[k=(l>>4)*8+j][n=l&15]
//   C/D: lane l reg r holds D[row=(l>>4)*4+r][col=l&15]
// mfma_f32_16x16x16_bf16 (K=16):
//   A: lane l holds A[m=l&15][k=(l>>4)*4+j]  <-- matches 16x16x32 C-layout
//   B: lane l holds B[k=(l>>4)*4+j][n=l&15]
// R9: (a) attn: mask row staged to LDS in prologue -> NO global loads in
// the main loop, so the counted vmcnt(2) is exact and the glds prefetch
// really stays in flight across the barrier (R8's in-loop mask loads were
// forcing compiler vmcnt(0) drains every tile). Compute phase split into
// {16 S^T MFMA} -> {pack} -> {PV MFMA} with s_setprio(1) around the MFMA
// clusters (T5). (b) qkv: BK=32, triple-buffered LDS, single s_barrier per
// step + counted vmcnt(4) -> staging of step s+1 overlaps MFMAs of step s.

typedef __bf16 bf16x8 __attribute__((ext_vector_type(8)));
typedef __bf16 bf16x4 __attribute__((ext_vector_type(4)));
typedef short  s16x4  __attribute__((ext_vector_type(4)));
typedef float  f32x4  __attribute__((ext_vector_type(4)));
typedef float  floatx4 __attribute__((ext_vector_type(4)));

#define MFMA16(a, b, c) __builtin_amdgcn_mfma_f32_16x16x32_bf16(a, b, c, 0, 0, 0)
// K=16 bf16 MFMA (gfx90a+ builtin, instruction present on gfx950 per ISA)
#define MFMA16K16(a, b, c) \
    __builtin_amdgcn_mfma_f32_16x16x16bf16_1k(a, b, c, 0, 0, 0)

#define WAITCNT_VM2() __builtin_amdgcn_s_waitcnt(0x0F72)   // vmcnt(2)
#define WAITCNT_VM4() __builtin_amdgcn_s_waitcnt(0x0F74)   // vmcnt(4)
#define BARRIER() __builtin_amdgcn_s_barrier()
#define SETPRIO(p) __builtin_amdgcn_s_setprio(p)

__device__ __forceinline__ void glds16(const __bf16* g, __bf16* l) {
    __builtin_amdgcn_global_load_lds(
        (const __attribute__((address_space(1))) void*)g,
        (__attribute__((address_space(3))) void*)l, 16, 0, 0);
}

// ---------------------------------------------------------------------------
// fp32 -> bf16 conversion: X (8M elems) then Wq/Wk/Wv (1M each).
// ---------------------------------------------------------------------------
__global__ __launch_bounds__(256) void convert_kernel(
    const float* __restrict__ X, const float* __restrict__ Wq,
    const float* __restrict__ Wk, const float* __restrict__ Wv,
    __bf16* __restrict__ Xb, __bf16* __restrict__ Wqb,
    __bf16* __restrict__ Wkb, __bf16* __restrict__ Wvb)
{
    int blk = blockIdx.x;
    const float* src; __bf16* dst; size_t base;
    if (blk < 4096)      { src = X;  dst = Xb;  base = (size_t)blk * 2048; }
    else if (blk < 4608) { src = Wq; dst = Wqb; base = (size_t)(blk - 4096) * 2048; }
    else if (blk < 5120) { src = Wk; dst = Wkb; base = (size_t)(blk - 4608) * 2048; }
    else                 { src = Wv; dst = Wvb; base = (size_t)(blk - 5120) * 2048; }
    size_t off = base + (size_t)threadIdx.x * 8;
    floatx4 a = *(const floatx4*)(src + off);
    floatx4 c = *(const floatx4*)(src + off + 4);
    bf16x8 o;
    o[0] = (__bf16)a[0]; o[1] = (__bf16)a[1]; o[2] = (__bf16)a[2]; o[3] = (__bf16)a[3];
    o[4] = (__bf16)c[0]; o[5] = (__bf16)c[1]; o[6] = (__bf16)c[2]; o[7] = (__bf16)c[3];
    *(bf16x8*)(dst + off) = o;
}

// ---------------------------------------------------------------------------
// Fused QKV GEMM: out = Xb @ Wb.T + bias. 128x128 tile, BK=32, triple-
// buffered glds staging, ONE s_barrier per K-step + counted vmcnt(4) so
// staging of step s+1 overlaps the MFMAs of step s.
// LDS layout per buffer: [128 rows][32 cols], 4 chunks of 8 bf16 per row,
// stored chunk ch holds global chunk ch ^ ((row>>1)&3)  (<=2-way = free).
// blockIdx.x: 0-7 -> Q, 8-15 -> K, 16-23 -> V(transposed).
// ---------------------------------------------------------------------------
__global__ __launch_bounds__(256) void qkv_gemm_kernel(
    const __bf16* __restrict__ Xb,
    const __bf16* __restrict__ Wqb, const __bf16* __restrict__ Wkb,
    const __bf16* __restrict__ Wvb,
    const float* __restrict__ bq, const float* __restrict__ bk,
    const float* __restrict__ bv,
    __bf16* __restrict__ qws, __bf16* __restrict__ kws, __bf16* __restrict__ vws)
{
    __shared__ __bf16 As[3][128 * 32];
    __shared__ __bf16 Bs[3][128 * 32];

    const int tid  = threadIdx.x;
    const int lane = tid & 63;
    const int wave = tid >> 6;
    const int wm   = (wave >> 1) * 64;
    const int wn   = (wave & 1) * 64;
    const int quad = lane >> 4;
    const int l16  = lane & 15;
    const int m0   = blockIdx.y * 128;

    const int sel = blockIdx.x >> 3;
    const bool vmode = (sel == 2);
    const __bf16* Wb = (sel == 0) ? Wqb : (sel == 1) ? Wkb : Wvb;
    const float* bias = (sel == 0) ? bq : (sel == 1) ? bk : bv;
    __bf16* outp = (sel == 0) ? qws : (sel == 1) ? kws : vws;
    const int n0 = (blockIdx.x & 7) * 128;

    const int woffA = vmode ? wm : wn;
    const int woffB = vmode ? wn : wm;

    // staging lane geometry: per glds, 64 lanes fill 16 rows x 32 cols.
    const int srow = lane >> 2;          // 0..15 row within 16-row block
    const int schk = lane & 3;           // LDS chunk this lane fills
    const int rchk = quad ^ ((l16 >> 1) & 3);   // frag-read chunk

    f32x4 acc[4][4] = {};

    // prologue: stage k-step 0 into buffer 0 (4 glds/wave)
    #pragma unroll
    for (int i = 0; i < 2; ++i) {
        int rb = wave * 32 + i * 16;
        int r  = rb + srow;
        int c  = schk ^ ((r >> 1) & 3);
        glds16(Xb + (size_t)(m0 + r) * 1024 + c * 8, &As[0][rb * 32]);
        glds16(Wb + (size_t)(n0 + r) * 1024 + c * 8, &Bs[0][rb * 32]);
    }

    int bc = 0, bn = 1, bx = 2;
    for (int s = 0; s < 32; ++s) {
        const int kn = ((s + 1) & 31) * 32;   // wrap: final restage benign
        #pragma unroll
        for (int i = 0; i < 2; ++i) {
            int rb = wave * 32 + i * 16;
            int r  = rb + srow;
            int c  = schk ^ ((r >> 1) & 3);
            glds16(Xb + (size_t)(m0 + r) * 1024 + kn + c * 8, &As[bn][rb * 32]);
            glds16(Wb + (size_t)(n0 + r) * 1024 + kn + c * 8, &Bs[bn][rb * 32]);
        }
        WAITCNT_VM4();          // step s's 4 glds (older) complete
        BARRIER();              // all waves' staging of step s visible

        const __bf16* Pa_ = vmode ? &As[bc][0] : &Bs[bc][0];
        const __bf16* Pb_ = vmode ? &Bs[bc][0] : &As[bc][0];

        SETPRIO(1);
        bf16x8 af[4], bfr[4];
        #pragma unroll
        for (int a = 0; a < 4; ++a)
            af[a] = *(const bf16x8*)&Pa_[(woffA + a * 16 + l16) * 32 + rchk * 8];
        #pragma unroll
        for (int bb = 0; bb < 4; ++bb)
            bfr[bb] = *(const bf16x8*)&Pb_[(woffB + bb * 16 + l16) * 32 + rchk * 8];
        #pragma unroll
        for (int a = 0; a < 4; ++a)
            #pragma unroll
            for (int bb = 0; bb < 4; ++bb)
                acc[a][bb] = MFMA16(af[a], bfr[bb], acc[a][bb]);
        SETPRIO(0);

        int tmp = bc; bc = bn; bn = bx; bx = tmp;
        // no trailing barrier: triple buffer -> next stage never touches
        // a buffer a laggard (at most 1 barrier behind) may still read.
    }

    if (!vmode) {
        #pragma unroll
        for (int a = 0; a < 4; ++a) {
            int n = n0 + woffA + a * 16 + quad * 4;
            floatx4 bv4 = *(const floatx4*)&bias[n];
            int h = n >> 6, d0 = n & 63;
            #pragma unroll
            for (int bb = 0; bb < 4; ++bb) {
                int m = m0 + woffB + bb * 16 + l16;
                int bt = m >> 11, ss = m & 2047;
                bf16x4 o;
                #pragma unroll
                for (int r = 0; r < 4; ++r)
                    o[r] = (__bf16)(acc[a][bb][r] + bv4[r]);
                *(bf16x4*)&outp[((size_t)(bt * 16 + h) * 2048 + ss) * 64 + d0] = o;
            }
        }
    } else {
        #pragma unroll
        for (int a = 0; a < 4; ++a) {
            int m = m0 + woffA + a * 16 + quad * 4;
            int bt = m >> 11, s0 = m & 2047;
            #pragma unroll
            for (int bb = 0; bb < 4; ++bb) {
                int n = n0 + woffB + bb * 16 + l16;
                float bvv = bias[n];
                int h = n >> 6, d = n & 63;
                bf16x4 o;
                #pragma unroll
                for (int r = 0; r < 4; ++r)
                    o[r] = (__bf16)(acc[a][bb][r] + bvv);
                *(bf16x4*)&outp[((size_t)(bt * 16 + h) * 64 + d) * 2048 + s0] = o;
            }
        }
    }
}

// ---------------------------------------------------------------------------
// Attention R9: grid (8, 64); 8 waves/block (512 thr), 32 q-rows per wave.
// Mask row (8KB) staged to LDS in the prologue -> zero global loads in the
// main loop, so vmcnt(2) exactly waits this tile's 2 glds and the next-tile
// prefetch crosses the barrier in flight. Compute split into phases:
// {all 16 S^T MFMA} -> {pack relu^2} -> {PV MFMA}, setprio(1) around MFMA.
// ---------------------------------------------------------------------------
__global__ __launch_bounds__(512, 4) void attn_kernel(
    const __bf16* __restrict__ Q, const __bf16* __restrict__ K,
    const __bf16* __restrict__ Vt, const float* __restrict__ mask,
    float* __restrict__ out)
{
    __shared__ __bf16 Ks[2][64 * 64];   // [key][d], XOR-swizzled chunks
    __shared__ __bf16 Vs[2][64 * 64];   // [d][key], XOR-swizzled chunks
    __shared__ float  Ms[2048];         // full mask row for this batch

    const int tid  = threadIdx.x;
    const int lane = tid & 63;
    const int wave = tid >> 6;          // 0..7
    const int quad = lane >> 4;
    const int l16  = lane & 15;
    const int bh   = blockIdx.y;
    const int b    = bh >> 4;
    const int h    = bh & 15;
    const int q0   = blockIdx.x * 256 + wave * 32;

    const __bf16* Qb = Q  + (size_t)bh * 2048 * 64;
    const __bf16* Kb = K  + (size_t)bh * 2048 * 64;
    const __bf16* Vb = Vt + (size_t)bh * 64 * 2048;
    const float*  mb = mask + b * 2048;

    // staging lane geometry: each wave fills 8 rows of K and 8 rows of V.
    const int rb = wave * 8;                       // LDS row base this wave
    const int sr = rb + (lane >> 3);               // row this lane reads
    const int sc = ((lane & 7) ^ (sr & 7)) * 8;    // swizzled elem offset

    // Q fragments (B operand for S^T): lane n=l16 -> q, k = 8 contiguous d.
    bf16x8 aq[2][2];
    #pragma unroll
    for (int qi = 0; qi < 2; ++qi)
        #pragma unroll
        for (int kcd = 0; kcd < 2; ++kcd)
            aq[qi][kcd] = *(const bf16x8*)(Qb +
                (size_t)(q0 + qi * 16 + l16) * 64 + kcd * 32 + quad * 8);

    f32x4 co[2][4] = {};   // ctx[q-tile][d-tile], rows=q, cols=d

    // ---- prologue: stage tile 0 (2 glds/wave) + mask row (1 glds/wave) ----
    glds16(Kb + (size_t)sr * 64 + sc, &Ks[0][rb * 64]);
    glds16(Vb + (size_t)sr * 2048 + sc, &Vs[0][rb * 64]);
    // wave w stages mask floats [w*256, w*256+256): 64 lanes x 16B = 1KB
    glds16((const __bf16*)mb + (size_t)wave * 512 + lane * 8,
           (__bf16*)Ms + wave * 512);

    for (int t = 0; t < 32; ++t) {
        const int k0 = t * 64;
        const int kn = ((t + 1) & 31) * 64;       // wrap: last restage benign
        const int nb = (t + 1) & 1;
        // ---- stage next tile (2 glds/wave) ----
        glds16(Kb + (size_t)(kn + sr) * 64 + sc, &Ks[nb][rb * 64]);
        glds16(Vb + (size_t)sr * 2048 + kn + sc, &Vs[nb][rb * 64]);
        WAITCNT_VM2();          // this tile's glds (older, + mask@t=0) done
        BARRIER();              // all waves' staging of tile t visible

        const __bf16* Kt = &Ks[t & 1][0];
        const __bf16* Vtile = &Vs[t & 1][0];

        // ---- phase 1: all S^T MFMAs (K Q^T) ----
        f32x4 st[4][2] = {};                       // [ki][qi]
        SETPRIO(1);
        #pragma unroll
        for (int ki = 0; ki < 4; ++ki) {
            #pragma unroll
            for (int kcd = 0; kcd < 2; ++kcd) {
                int key = ki * 16 + l16;
                bf16x8 ak = *(const bf16x8*)&Kt[key * 64 +
                    (((kcd * 4 + quad) ^ (key & 7)) * 8)];
                #pragma unroll
                for (int qi = 0; qi < 2; ++qi)
                    st[ki][qi] = MFMA16(ak, aq[qi][kcd], st[ki][qi]);
            }
        }
        SETPRIO(0);

        // ---- phase 2: relu^2 pack into PV A-frags (mask from LDS) ----
        bf16x4 pf[4][2];                           // [ki][qi]
        #pragma unroll
        for (int ki = 0; ki < 4; ++ki) {
            floatx4 mk = *(const floatx4*)&Ms[k0 + ki * 16 + quad * 4];
            #pragma unroll
            for (int qi = 0; qi < 2; ++qi) {
                bf16x4 pv;
                #pragma unroll
                for (int r = 0; r < 4; ++r) {
                    float x = st[ki][qi][r] * 0.125f + mk[r];
                    x = fmaxf(x, 0.0f);
                    pv[r] = (__bf16)(x * x);
                }
                pf[ki][qi] = pv;
            }
        }

        // ---- phase 3: PV: ctx[q][d] += P V via 16x16x16 (A in registers) --
        SETPRIO(1);
        #pragma unroll
        for (int ki = 0; ki < 4; ++ki) {
            bf16x4 vb4[4];
            #pragma unroll
            for (int dt = 0; dt < 4; ++dt) {
                int d = dt * 16 + l16;
                int g = ki * 2 + (quad >> 1);       // global 8-elem chunk
                vb4[dt] = *(const bf16x4*)&Vtile[d * 64 +
                    ((g ^ (d & 7)) * 8) + (quad & 1) * 4];
            }
            #pragma unroll
            for (int qi = 0; qi < 2; ++qi) {
                s16x4 pa = __builtin_bit_cast(s16x4, pf[ki][qi]);
                #pragma unroll
                for (int dt = 0; dt < 4; ++dt)
                    co[qi][dt] = MFMA16K16(pa,
                        __builtin_bit_cast(s16x4, vb4[dt]), co[qi][dt]);
            }
        }
        SETPRIO(0);
        BARRIER();              // everyone done reading buf t before overwrite
    }

    // Epilogue: ctx row = q = qi*16+quad*4+r, col = d = dt*16+l16.
    #pragma unroll
    for (int qi = 0; qi < 2; ++qi)
        #pragma unroll
        for (int r = 0; r < 4; ++r) {
            int q = q0 + qi * 16 + quad * 4 + r;
            float* orow = &out[(((size_t)b * 2048 + q) * 16 + h) * 64];
            #pragma unroll
            for (int dt = 0; dt < 4; ++dt)
                orow[dt * 16 + l16] = co[qi][dt][r];
        }
}

// ---------------------------------------------------------------------------
extern "C" void kernel_launch(void* const* d_in, const int* in_sizes, int n_in,
                              void* d_out, int out_size, void* d_ws, size_t ws_size,
                              hipStream_t stream) {
    const float* hidden = (const float*)d_in[0];   // [4,2048,1024]
    const float* mask   = (const float*)d_in[1];   // [4,1,1,2048]
    const float* Wq     = (const float*)d_in[2];
    const float* bq     = (const float*)d_in[3];
    const float* Wk     = (const float*)d_in[4];
    const float* bk     = (const float*)d_in[5];
    const float* Wv     = (const float*)d_in[6];
    const float* bv     = (const float*)d_in[7];
    float* out = (float*)d_out;

    __bf16* qws = (__bf16*)d_ws;                       // [64][2048][64]
    __bf16* kws = qws + (size_t)64 * 2048 * 64;        // [64][2048][64]
    __bf16* vws = kws + (size_t)64 * 2048 * 64;        // [64][64][2048]
    __bf16* Xb  = vws + (size_t)64 * 2048 * 64;        // [8192][1024]
    __bf16* Wqb = Xb  + (size_t)8192 * 1024;
    __bf16* Wkb = Wqb + (size_t)1024 * 1024;
    __bf16* Wvb = Wkb + (size_t)1024 * 1024;

    convert_kernel<<<dim3(5632), dim3(256), 0, stream>>>(hidden, Wq, Wk, Wv,
                                                         Xb, Wqb, Wkb, Wvb);
    qkv_gemm_kernel<<<dim3(24, 64), dim3(256), 0, stream>>>(Xb, Wqb, Wkb, Wvb,
                                                            bq, bk, bv,
                                                            qws, kws, vws);
    attn_kernel<<<dim3(8, 64), dim3(512), 0, stream>>>(qws, kws, vws, mask, out);
}

// Round 3
// 250.184 us; speedup vs baseline: 1.0883x; 1.0746x over previous
//
#include <hip/hip_runtime.h>

// MI355X / gfx950. bf16 MFMA BERT attention with relu^2 "softmax".
// mfma_f32_16x16x32_bf16 layouts (HW-verified):
//   A: lane l holds A[m=l&15][k=(l>>4)*8+j]
//   B: lane l holds B[k=(l>>4)*8+j][n=l&15]
//   C/D: lane l reg r holds D[row=(l>>4)*4+r][col=l&15]
// mfma_f32_16x16x16_bf16 (K=16):
//   A: lane l holds A[m=l&15][k=(l>>4)*4+j]  <-- matches 16x16x32 C-layout
// R10: (a) qkv back to BK=64/32KB (5 blocks/CU) but restructured to the
// T3-minimal single-barrier dbuf: {stage(s+1); MFMA(s); vmcnt(0); barrier}
// -- prefetch spans the compute, no drain-before-compute (R9's BK=32
// triple-buffer cut occupancy 5->3 blocks/CU and regressed). (b) attn grid
// (8,64)->(64,8): all 8 q-tiles of one head land on XCD bh%8 -> K/V
// fetched once per L2 instead of per-XCD copies (FETCH 143MB -> ~ideal).
// (c) attn relu^2 pack phase in f32x4 vector expressions -> v_pk_* f32.

typedef __bf16 bf16x8 __attribute__((ext_vector_type(8)));
typedef __bf16 bf16x4 __attribute__((ext_vector_type(4)));
typedef short  s16x4  __attribute__((ext_vector_type(4)));
typedef float  f32x4  __attribute__((ext_vector_type(4)));
typedef float  floatx4 __attribute__((ext_vector_type(4)));

#define MFMA16(a, b, c) __builtin_amdgcn_mfma_f32_16x16x32_bf16(a, b, c, 0, 0, 0)
// K=16 bf16 MFMA (gfx90a+ builtin, instruction present on gfx950 per ISA)
#define MFMA16K16(a, b, c) \
    __builtin_amdgcn_mfma_f32_16x16x16bf16_1k(a, b, c, 0, 0, 0)

#define WAITCNT_VM0() __builtin_amdgcn_s_waitcnt(0x0F70)   // vmcnt(0)
#define WAITCNT_VM2() __builtin_amdgcn_s_waitcnt(0x0F72)   // vmcnt(2)
#define BARRIER() __builtin_amdgcn_s_barrier()
#define SETPRIO(p) __builtin_amdgcn_s_setprio(p)

__device__ __forceinline__ void glds16(const __bf16* g, __bf16* l) {
    __builtin_amdgcn_global_load_lds(
        (const __attribute__((address_space(1))) void*)g,
        (__attribute__((address_space(3))) void*)l, 16, 0, 0);
}

// ---------------------------------------------------------------------------
// fp32 -> bf16 conversion: X (8M elems) then Wq/Wk/Wv (1M each).
// ---------------------------------------------------------------------------
__global__ __launch_bounds__(256) void convert_kernel(
    const float* __restrict__ X, const float* __restrict__ Wq,
    const float* __restrict__ Wk, const float* __restrict__ Wv,
    __bf16* __restrict__ Xb, __bf16* __restrict__ Wqb,
    __bf16* __restrict__ Wkb, __bf16* __restrict__ Wvb)
{
    int blk = blockIdx.x;
    const float* src; __bf16* dst; size_t base;
    if (blk < 4096)      { src = X;  dst = Xb;  base = (size_t)blk * 2048; }
    else if (blk < 4608) { src = Wq; dst = Wqb; base = (size_t)(blk - 4096) * 2048; }
    else if (blk < 5120) { src = Wk; dst = Wkb; base = (size_t)(blk - 4608) * 2048; }
    else                 { src = Wv; dst = Wvb; base = (size_t)(blk - 5120) * 2048; }
    size_t off = base + (size_t)threadIdx.x * 8;
    floatx4 a = *(const floatx4*)(src + off);
    floatx4 c = *(const floatx4*)(src + off + 4);
    bf16x8 o;
    o[0] = (__bf16)a[0]; o[1] = (__bf16)a[1]; o[2] = (__bf16)a[2]; o[3] = (__bf16)a[3];
    o[4] = (__bf16)c[0]; o[5] = (__bf16)c[1]; o[6] = (__bf16)c[2]; o[7] = (__bf16)c[3];
    *(bf16x8*)(dst + off) = o;
}

// ---------------------------------------------------------------------------
// Fused QKV GEMM: out = Xb @ Wb.T + bias. 128x128 tile, BK=64, double-
// buffered glds staging, ONE s_barrier per K-step (T3-minimal):
//   { stage(s+1 -> nb); frag-read + 32 MFMA on bc; vmcnt(0); barrier }
// Race-free: stage writes buf (s+1)&1 while all waves read s&1; buf s&1 is
// only overwritten at iter s+2's stage, after barrier(s+1).
// blockIdx.x: 0-7 -> Q, 8-15 -> K, 16-23 -> V(transposed).
// ---------------------------------------------------------------------------
__global__ __launch_bounds__(256) void qkv_gemm_kernel(
    const __bf16* __restrict__ Xb,
    const __bf16* __restrict__ Wqb, const __bf16* __restrict__ Wkb,
    const __bf16* __restrict__ Wvb,
    const float* __restrict__ bq, const float* __restrict__ bk,
    const float* __restrict__ bv,
    __bf16* __restrict__ qws, __bf16* __restrict__ kws, __bf16* __restrict__ vws)
{
    __shared__ __bf16 As[2][128 * 64];
    __shared__ __bf16 Bs[2][128 * 64];

    const int tid  = threadIdx.x;
    const int lane = tid & 63;
    const int wave = tid >> 6;
    const int wm   = (wave >> 1) * 64;
    const int wn   = (wave & 1) * 64;
    const int quad = lane >> 4;
    const int l16  = lane & 15;
    const int m0   = blockIdx.y * 128;

    const int sel = blockIdx.x >> 3;
    const bool vmode = (sel == 2);
    const __bf16* Wb = (sel == 0) ? Wqb : (sel == 1) ? Wkb : Wvb;
    const float* bias = (sel == 0) ? bq : (sel == 1) ? bk : bv;
    __bf16* outp = (sel == 0) ? qws : (sel == 1) ? kws : vws;
    const int n0 = (blockIdx.x & 7) * 128;

    const int woffA = vmode ? wm : wn;
    const int woffB = vmode ? wn : wm;

    // staging lane geometry: one glds fills 8 rows x 64 cols (1KB).
    const int srow = lane >> 3;              // row within 8-row block
    const int schk = lane & 7;               // 16B chunk this lane fills

    f32x4 acc[4][4] = {};

    // ---- prologue: stage k-step 0 into buffer 0 (8 glds/wave) ----
    #pragma unroll
    for (int i = 0; i < 4; ++i) {
        int rb = wave * 32 + i * 8;
        int r  = rb + srow;
        int c  = schk ^ (r & 7);
        glds16(Xb + (size_t)(m0 + r) * 1024 + c * 8, &As[0][rb * 64]);
        glds16(Wb + (size_t)(n0 + r) * 1024 + c * 8, &Bs[0][rb * 64]);
    }
    WAITCNT_VM0();
    BARRIER();

    for (int s = 0; s < 16; ++s) {
        const int kn = ((s + 1) & 15) * 64;   // wrap: final restage benign
        const int nb = (s + 1) & 1;
        const int bc = s & 1;
        // ---- stage next k-step (8 glds/wave) ----
        #pragma unroll
        for (int i = 0; i < 4; ++i) {
            int rb = wave * 32 + i * 8;
            int r  = rb + srow;
            int c  = schk ^ (r & 7);
            glds16(Xb + (size_t)(m0 + r) * 1024 + kn + c * 8, &As[nb][rb * 64]);
            glds16(Wb + (size_t)(n0 + r) * 1024 + kn + c * 8, &Bs[nb][rb * 64]);
        }

        const __bf16* Pa_ = vmode ? &As[bc][0] : &Bs[bc][0];
        const __bf16* Pb_ = vmode ? &Bs[bc][0] : &As[bc][0];

        SETPRIO(1);
        #pragma unroll
        for (int kk8 = 0; kk8 < 8; kk8 += 4) {
            bf16x8 af[4], bfr[4];
            #pragma unroll
            for (int a = 0; a < 4; ++a)
                af[a] = *(const bf16x8*)&Pa_[(woffA + a * 16 + l16) * 64 +
                                             (((kk8 + quad) ^ (l16 & 7)) * 8)];
            #pragma unroll
            for (int bb = 0; bb < 4; ++bb)
                bfr[bb] = *(const bf16x8*)&Pb_[(woffB + bb * 16 + l16) * 64 +
                                               (((kk8 + quad) ^ (l16 & 7)) * 8)];
            #pragma unroll
            for (int a = 0; a < 4; ++a)
                #pragma unroll
                for (int bb = 0; bb < 4; ++bb)
                    acc[a][bb] = MFMA16(af[a], bfr[bb], acc[a][bb]);
        }
        SETPRIO(0);

        WAITCNT_VM0();          // this iter's stage (issued ~full compute ago)
        BARRIER();              // buf nb fully written before anyone reads it
    }

    if (!vmode) {
        #pragma unroll
        for (int a = 0; a < 4; ++a) {
            int n = n0 + woffA + a * 16 + quad * 4;
            floatx4 bv4 = *(const floatx4*)&bias[n];
            int h = n >> 6, d0 = n & 63;
            #pragma unroll
            for (int bb = 0; bb < 4; ++bb) {
                int m = m0 + woffB + bb * 16 + l16;
                int bt = m >> 11, ss = m & 2047;
                bf16x4 o;
                #pragma unroll
                for (int r = 0; r < 4; ++r)
                    o[r] = (__bf16)(acc[a][bb][r] + bv4[r]);
                *(bf16x4*)&outp[((size_t)(bt * 16 + h) * 2048 + ss) * 64 + d0] = o;
            }
        }
    } else {
        #pragma unroll
        for (int a = 0; a < 4; ++a) {
            int m = m0 + woffA + a * 16 + quad * 4;
            int bt = m >> 11, s0 = m & 2047;
            #pragma unroll
            for (int bb = 0; bb < 4; ++bb) {
                int n = n0 + woffB + bb * 16 + l16;
                float bvv = bias[n];
                int h = n >> 6, d = n & 63;
                bf16x4 o;
                #pragma unroll
                for (int r = 0; r < 4; ++r)
                    o[r] = (__bf16)(acc[a][bb][r] + bvv);
                *(bf16x4*)&outp[((size_t)(bt * 16 + h) * 64 + d) * 2048 + s0] = o;
            }
        }
    }
}

// ---------------------------------------------------------------------------
// Attention R10: grid (64, 8) -- blockIdx.x = head (bh), blockIdx.y = q-tile.
// Linear block id = bh + 64*qt -> XCD = bh%8: all 8 q-tile blocks sharing one
// head's K/V (512KB) live on ONE XCD's L2 (8 heads x 512KB = 4MB = L2 size).
// 8 waves/block, 32 q-rows/wave; mask row in LDS (no global loads in loop);
// vmcnt(2)-counted glds double-buffer; phases {S^T MFMA}{pack}{PV MFMA} with
// setprio; pack phase in f32x4 vector ops -> packed v_pk_* f32 math.
// ---------------------------------------------------------------------------
__global__ __launch_bounds__(512, 4) void attn_kernel(
    const __bf16* __restrict__ Q, const __bf16* __restrict__ K,
    const __bf16* __restrict__ Vt, const float* __restrict__ mask,
    float* __restrict__ out)
{
    __shared__ __bf16 Ks[2][64 * 64];   // [key][d], XOR-swizzled chunks
    __shared__ __bf16 Vs[2][64 * 64];   // [d][key], XOR-swizzled chunks
    __shared__ float  Ms[2048];         // full mask row for this batch

    const int tid  = threadIdx.x;
    const int lane = tid & 63;
    const int wave = tid >> 6;          // 0..7
    const int quad = lane >> 4;
    const int l16  = lane & 15;
    const int bh   = blockIdx.x;        // head index -> XCD = bh % 8
    const int b    = bh >> 4;
    const int h    = bh & 15;
    const int q0   = blockIdx.y * 256 + wave * 32;

    const __bf16* Qb = Q  + (size_t)bh * 2048 * 64;
    const __bf16* Kb = K  + (size_t)bh * 2048 * 64;
    const __bf16* Vb = Vt + (size_t)bh * 64 * 2048;
    const float*  mb = mask + b * 2048;

    // staging lane geometry: each wave fills 8 rows of K and 8 rows of V.
    const int rb = wave * 8;                       // LDS row base this wave
    const int sr = rb + (lane >> 3);               // row this lane reads
    const int sc = ((lane & 7) ^ (sr & 7)) * 8;    // swizzled elem offset

    // Q fragments (B operand for S^T): lane n=l16 -> q, k = 8 contiguous d.
    bf16x8 aq[2][2];
    #pragma unroll
    for (int qi = 0; qi < 2; ++qi)
        #pragma unroll
        for (int kcd = 0; kcd < 2; ++kcd)
            aq[qi][kcd] = *(const bf16x8*)(Qb +
                (size_t)(q0 + qi * 16 + l16) * 64 + kcd * 32 + quad * 8);

    f32x4 co[2][4] = {};   // ctx[q-tile][d-tile], rows=q, cols=d

    // ---- prologue: stage tile 0 (2 glds/wave) + mask row (1 glds/wave) ----
    glds16(Kb + (size_t)sr * 64 + sc, &Ks[0][rb * 64]);
    glds16(Vb + (size_t)sr * 2048 + sc, &Vs[0][rb * 64]);
    // wave w stages mask floats [w*256, w*256+256): 64 lanes x 16B = 1KB
    glds16((const __bf16*)mb + (size_t)wave * 512 + lane * 8,
           (__bf16*)Ms + wave * 512);

    for (int t = 0; t < 32; ++t) {
        const int k0 = t * 64;
        const int kn = ((t + 1) & 31) * 64;       // wrap: last restage benign
        const int nb = (t + 1) & 1;
        // ---- stage next tile (2 glds/wave) ----
        glds16(Kb + (size_t)(kn + sr) * 64 + sc, &Ks[nb][rb * 64]);
        glds16(Vb + (size_t)sr * 2048 + kn + sc, &Vs[nb][rb * 64]);
        WAITCNT_VM2();          // this tile's glds (older, + mask@t=0) done
        BARRIER();              // all waves' staging of tile t visible

        const __bf16* Kt = &Ks[t & 1][0];
        const __bf16* Vtile = &Vs[t & 1][0];

        // ---- phase 1: all S^T MFMAs (K Q^T) ----
        f32x4 st[4][2] = {};                       // [ki][qi]
        SETPRIO(1);
        #pragma unroll
        for (int ki = 0; ki < 4; ++ki) {
            #pragma unroll
            for (int kcd = 0; kcd < 2; ++kcd) {
                int key = ki * 16 + l16;
                bf16x8 ak = *(const bf16x8*)&Kt[key * 64 +
                    (((kcd * 4 + quad) ^ (key & 7)) * 8)];
                #pragma unroll
                for (int qi = 0; qi < 2; ++qi)
                    st[ki][qi] = MFMA16(ak, aq[qi][kcd], st[ki][qi]);
            }
        }
        SETPRIO(0);

        // ---- phase 2: relu^2 pack into PV A-frags (vector f32 math) ----
        bf16x4 pf[4][2];                           // [ki][qi]
        const f32x4 zero4 = {};
        #pragma unroll
        for (int ki = 0; ki < 4; ++ki) {
            f32x4 mk = *(const f32x4*)&Ms[k0 + ki * 16 + quad * 4];
            #pragma unroll
            for (int qi = 0; qi < 2; ++qi) {
                f32x4 x = st[ki][qi] * 0.125f + mk;     // v_pk_fma_f32
                x = __builtin_elementwise_max(x, zero4); // v_pk_max_f32
                x = x * x;                               // v_pk_mul_f32
                bf16x4 pv;
                pv[0] = (__bf16)x[0]; pv[1] = (__bf16)x[1];
                pv[2] = (__bf16)x[2]; pv[3] = (__bf16)x[3];
                pf[ki][qi] = pv;
            }
        }

        // ---- phase 3: PV: ctx[q][d] += P V via 16x16x16 (A in registers) --
        SETPRIO(1);
        #pragma unroll
        for (int ki = 0; ki < 4; ++ki) {
            bf16x4 vb4[4];
            #pragma unroll
            for (int dt = 0; dt < 4; ++dt) {
                int d = dt * 16 + l16;
                int g = ki * 2 + (quad >> 1);       // global 8-elem chunk
                vb4[dt] = *(const bf16x4*)&Vtile[d * 64 +
                    ((g ^ (d & 7)) * 8) + (quad & 1) * 4];
            }
            #pragma unroll
            for (int qi = 0; qi < 2; ++qi) {
                s16x4 pa = __builtin_bit_cast(s16x4, pf[ki][qi]);
                #pragma unroll
                for (int dt = 0; dt < 4; ++dt)
                    co[qi][dt] = MFMA16K16(pa,
                        __builtin_bit_cast(s16x4, vb4[dt]), co[qi][dt]);
            }
        }
        SETPRIO(0);
        BARRIER();              // everyone done reading buf t before overwrite
    }

    // Epilogue: ctx row = q = qi*16+quad*4+r, col = d = dt*16+l16.
    #pragma unroll
    for (int qi = 0; qi < 2; ++qi)
        #pragma unroll
        for (int r = 0; r < 4; ++r) {
            int q = q0 + qi * 16 + quad * 4 + r;
            float* orow = &out[(((size_t)b * 2048 + q) * 16 + h) * 64];
            #pragma unroll
            for (int dt = 0; dt < 4; ++dt)
                orow[dt * 16 + l16] = co[qi][dt][r];
        }
}

// ---------------------------------------------------------------------------
extern "C" void kernel_launch(void* const* d_in, const int* in_sizes, int n_in,
                              void* d_out, int out_size, void* d_ws, size_t ws_size,
                              hipStream_t stream) {
    const float* hidden = (const float*)d_in[0];   // [4,2048,1024]
    const float* mask   = (const float*)d_in[1];   // [4,1,1,2048]
    const float* Wq     = (const float*)d_in[2];
    const float* bq     = (const float*)d_in[3];
    const float* Wk     = (const float*)d_in[4];
    const float* bk     = (const float*)d_in[5];
    const float* Wv     = (const float*)d_in[6];
    const float* bv     = (const float*)d_in[7];
    float* out = (float*)d_out;

    __bf16* qws = (__bf16*)d_ws;                       // [64][2048][64]
    __bf16* kws = qws + (size_t)64 * 2048 * 64;        // [64][2048][64]
    __bf16* vws = kws + (size_t)64 * 2048 * 64;        // [64][64][2048]
    __bf16* Xb  = vws + (size_t)64 * 2048 * 64;        // [8192][1024]
    __bf16* Wqb = Xb  + (size_t)8192 * 1024;
    __bf16* Wkb = Wqb + (size_t)1024 * 1024;
    __bf16* Wvb = Wkb + (size_t)1024 * 1024;

    convert_kernel<<<dim3(5632), dim3(256), 0, stream>>>(hidden, Wq, Wk, Wv,
                                                         Xb, Wqb, Wkb, Wvb);
    qkv_gemm_kernel<<<dim3(24, 64), dim3(256), 0, stream>>>(Xb, Wqb, Wkb, Wvb,
                                                            bq, bk, bv,
                                                            qws, kws, vws);
    attn_kernel<<<dim3(64, 8), dim3(512), 0, stream>>>(qws, kws, vws, mask, out);
}